// Round 10
// baseline (704.514 us; speedup 1.0000x reference)
//
#include <hip/hip_runtime.h>

typedef _Float16 h8_t __attribute__((ext_vector_type(8)));
typedef _Float16 h4_t __attribute__((ext_vector_type(4)));
typedef float f4_t __attribute__((ext_vector_type(4)));

#define NTOK 9216
#define CMID 128
#define NBATCH 2
#define KCHUNK 5                  // 720 blocks: all resident at 3 blocks/CU
#define NKT 144                   // 64-key tiles per batch
#define NSTAT 18432.0f            // 2*9216 elements per channel for BN stats

// MFMA fragment recipe (verified R2-R9):
//   A-frag: lane(l16,quad) holds A[m=l16][k=quad*8+j]   (h8 from [m][k] row)
//   B-frag: lane(l16,quad) holds B[n=l16][k=quad*8+j]   (h8 from [n][k] row)
//   D:      lane(l16,quad) holds D[row=quad*4+r][col=l16]
// R8 lesson: W frags must be LDS-staged; per-lane global loads inside the
// MFMA loop put L2 latency on the critical path (348->377 regression).
// R6 lesson: unified VGPR+AGPR cap (512/waves-per-SIMD); overshoot = scratch
// spills, signature = FETCH_SIZE explosion.

__device__ __forceinline__ h8_t cvt_f32x8_h8(const float* p) {
  f4_t a = *(const f4_t*)p, b = *(const f4_t*)(p + 4);
  h8_t h;
#pragma unroll
  for (int u = 0; u < 4; u++) { h[u] = (_Float16)a[u]; h[u + 4] = (_Float16)b[u]; }
  return h;
}

// ---------------------------------------------------------------------------
// Kernel A: QKV projection via MFMA (FROZEN from R9).
// ---------------------------------------------------------------------------
__global__ __launch_bounds__(256) void qkv_kernel(
    const float* __restrict__ x, const float* __restrict__ Wk,
    const float* __restrict__ Wv, const float* __restrict__ Wq,
    _Float16* __restrict__ Qt, _Float16* __restrict__ Kt,
    _Float16* __restrict__ V)
{
  const int b  = blockIdx.z;
  const int n0 = blockIdx.x * 64;
  const int o0 = blockIdx.y * 64;
  const int tid = threadIdx.x;
  const int wave = tid >> 6, lane = tid & 63, quad = lane >> 4, l16 = lane & 15;

  __shared__ _Float16 Wl[64][136];   // A tile [o][c-chunk]
  __shared__ _Float16 xl[64][136];   // B tile [n][c-chunk]
  __shared__ _Float16 Tt[128][68];   // transpose staging (f16)

  const float* Wsel; int orow;
  if (o0 < 128)      { Wsel = Wq; orow = o0; }
  else if (o0 < 256) { Wsel = Wk; orow = o0 - 128; }
  else               { Wsel = Wv; orow = o0 - 256; }

  f4_t acc[4];
#pragma unroll
  for (int t = 0; t < 4; t++) acc[t] = (f4_t)(0.f);

  for (int kc = 0; kc < 256; kc += 128) {
    __syncthreads();
#pragma unroll
    for (int it = 0; it < 4; it++) {
      int idx = tid + it * 256;
      int row = idx >> 4, oc = idx & 15;
      *(h8_t*)&Wl[row][oc * 8] =
          cvt_f32x8_h8(&Wsel[(size_t)(orow + row) * 256 + kc + oc * 8]);
    }
#pragma unroll
    for (int it = 0; it < 8; it++) {
      int idx = tid + it * 256;
      int cl = idx >> 4, u = idx & 15;
      f4_t v = *(const f4_t*)&x[(size_t)(b * 256 + kc + cl) * NTOK + n0 + u * 4];
      h4_t h;
#pragma unroll
      for (int j = 0; j < 4; j++) h[j] = (_Float16)v[j];
      *(h4_t*)&Tt[cl][u * 4] = h;
    }
    __syncthreads();
#pragma unroll
    for (int it = 0; it < 4; it++) {
      int idx = tid + it * 256;
      int nl = idx & 63, oc = idx >> 6;   // oc 0..15
      h8_t h;
#pragma unroll
      for (int j = 0; j < 8; j++) h[j] = Tt[oc * 8 + j][nl];
      *(h8_t*)&xl[nl][oc * 8] = h;
    }
    __syncthreads();
#pragma unroll
    for (int ko = 0; ko < 4; ko++) {
      h8_t af = *(const h8_t*)&Wl[wave * 16 + l16][ko * 32 + quad * 8];
#pragma unroll
      for (int t = 0; t < 4; t++) {
        h8_t bf = *(const h8_t*)&xl[t * 16 + l16][ko * 32 + quad * 8];
        acc[t] = __builtin_amdgcn_mfma_f32_16x16x32_f16(af, bf, acc[t], 0, 0, 0);
      }
    }
  }

  const float qscale = 0.08838834764831845f * 1.4426950408889634f; // 128^-0.5*log2e
  if (o0 < 256) {
    _Float16* dst = (o0 < 128) ? Qt : Kt;
    const int od = ((o0 < 128) ? o0 : (o0 - 128)) + wave * 16 + quad * 4;
    const float s = (o0 < 128) ? qscale : 1.0f;
#pragma unroll
    for (int t = 0; t < 4; t++) {
      int n = n0 + t * 16 + l16;
      h4_t h;
#pragma unroll
      for (int r = 0; r < 4; r++) h[r] = (_Float16)(acc[t][r] * s);
      *(h4_t*)&dst[(size_t)(b * NTOK + n) * CMID + od] = h;
    }
  } else {
    const int c0 = o0 - 256 + wave * 16 + quad * 4;
#pragma unroll
    for (int t = 0; t < 4; t++) {
      int n = n0 + t * 16 + l16;
#pragma unroll
      for (int r = 0; r < 4; r++)
        V[(size_t)(b * CMID + c0 + r) * NTOK + n] = (_Float16)acc[t][r];
    }
  }
}

// ---------------------------------------------------------------------------
// Kernel B v5: split-K flash.
//  - XOR-swizzled LDS (no pads): Kl[64][128] chunk^=row&15; Vl/Pl[.][64]
//    chunk^=row&7. All b128 frag reads 2-way (free per m136). 48 KB total.
//  - Pl separate (wave-private rows) -> B3 barrier ELIMINATED (2 barriers).
//  - K/V register prefetch issued after Pl writes: L2 latency overlaps
//    O-phase + barrier wait. Peak regs ~100 arch + 64 AGPR < 170 cap.
// ---------------------------------------------------------------------------
__global__ __launch_bounds__(256, 3) void flash_kernel(
    const _Float16* __restrict__ Qt, const _Float16* __restrict__ Kt,
    const _Float16* __restrict__ V,
    float* __restrict__ gcn_acc, float* __restrict__ l_acc)
{
  const int b  = blockIdx.z;
  const int kc = blockIdx.y;
  const int q0 = blockIdx.x * 128;
  const int tid = threadIdx.x;
  const int wave = tid >> 6, lane = tid & 63, quad = lane >> 4, l16 = lane & 15;

  __shared__ alignas(16) _Float16 Kl[64 * 128];   // [key][c]  swizzled
  __shared__ alignas(16) _Float16 Vl[128 * 64];   // [c][key]  swizzled
  __shared__ alignas(16) _Float16 Pl[128 * 64];   // [q][key]  swizzled, wave-private

  h8_t qf[2][4];
#pragma unroll
  for (int qi = 0; qi < 2; qi++) {
    const _Float16* qp =
        Qt + (size_t)(b * NTOK + q0 + wave * 32 + qi * 16 + l16) * CMID;
#pragma unroll
    for (int ch = 0; ch < 4; ch++)
      qf[qi][ch] = *(const h8_t*)(qp + ch * 32 + quad * 8);
  }

  f4_t O[2][8];
#pragma unroll
  for (int qi = 0; qi < 2; qi++)
#pragma unroll
    for (int t = 0; t < 8; t++) O[qi][t] = (f4_t)(0.f);
  float l_r[2][4] = {{0.f, 0.f, 0.f, 0.f}, {0.f, 0.f, 0.f, 0.f}};

  const int t0 = (kc * NKT) / KCHUNK;
  const int t1 = ((kc + 1) * NKT) / KCHUNK;
  const int k_end = t1 * 64;

  h8_t kpre[4], vpre[4];
  {  // prologue prefetch (tile t0)
    const h8_t* src = (const h8_t*)(Kt + (size_t)(b * NTOK + t0 * 64) * CMID);
#pragma unroll
    for (int r = 0; r < 4; r++) kpre[r] = src[tid + r * 256];
    const _Float16* vs = V + (size_t)(b * CMID) * NTOK + t0 * 64;
#pragma unroll
    for (int r = 0; r < 4; r++) {
      int idx = tid + r * 256;
      vpre[r] = *(const h8_t*)(vs + (size_t)(idx >> 3) * NTOK + (idx & 7) * 8);
    }
  }

  for (int k0 = t0 * 64; k0 < k_end; k0 += 64) {
    __syncthreads();   // B1: all waves done reading Kl/Vl of prior tile
    // write prefetched tiles (vmcnt drain), swizzled placement
#pragma unroll
    for (int r = 0; r < 4; r++) {
      int idx = tid + r * 256;
      int row = idx >> 4, ch = idx & 15;                 // Kl: key row, c-chunk
      *(h8_t*)&Kl[row * 128 + ((ch ^ row) & 15) * 8] = kpre[r];
    }
#pragma unroll
    for (int r = 0; r < 4; r++) {
      int idx = tid + r * 256;
      int row = idx >> 3, ch = idx & 7;                  // Vl: c row, key-chunk
      *(h8_t*)&Vl[row * 64 + ((ch ^ row) & 7) * 8] = vpre[r];
    }
    __syncthreads();   // B2: tiles staged

    // S = Q^T K : wave computes 32q x 64k
    f4_t S[2][4];
#pragma unroll
    for (int qi = 0; qi < 2; qi++)
#pragma unroll
      for (int t = 0; t < 4; t++) S[qi][t] = (f4_t)(0.f);
#pragma unroll
    for (int ch = 0; ch < 4; ch++)
#pragma unroll
      for (int t = 0; t < 4; t++) {
        int chunk = ch * 4 + quad;                       // c/8; row&15 == l16
        h8_t kf = *(const h8_t*)&Kl[(t * 16 + l16) * 128 + ((chunk ^ l16) & 15) * 8];
        S[0][t] = __builtin_amdgcn_mfma_f32_16x16x32_f16(qf[0][ch], kf, S[0][t], 0, 0, 0);
        S[1][t] = __builtin_amdgcn_mfma_f32_16x16x32_f16(qf[1][ch], kf, S[1][t], 0, 0, 0);
      }

    // p = 2^(S-8); accumulate l; write P (wave-private rows, no barrier)
#pragma unroll
    for (int qi = 0; qi < 2; qi++)
#pragma unroll
      for (int t = 0; t < 4; t++)
#pragma unroll
        for (int r = 0; r < 4; r++) {
          float p = exp2f(S[qi][t][r] - 8.0f);
          l_r[qi][r] += p;
          int q = wave * 32 + qi * 16 + quad * 4 + r;
          int key = t * 16 + l16;
          Pl[q * 64 + (((key >> 3) ^ q) & 7) * 8 + (key & 7)] = (_Float16)p;
        }

    // prefetch next tile: latency hides behind O-phase + next barrier wait
    if (k0 + 64 < k_end) {
      const h8_t* src = (const h8_t*)(Kt + (size_t)(b * NTOK + k0 + 64) * CMID);
#pragma unroll
      for (int r = 0; r < 4; r++) kpre[r] = src[tid + r * 256];
      const _Float16* vs = V + (size_t)(b * CMID) * NTOK + k0 + 64;
#pragma unroll
      for (int r = 0; r < 4; r++) {
        int idx = tid + r * 256;
        vpre[r] = *(const h8_t*)(vs + (size_t)(idx >> 3) * NTOK + (idx & 7) * 8);
      }
    }

    // O += P V^T
#pragma unroll
    for (int ch = 0; ch < 2; ch++) {
      int chunk = ch * 4 + quad;                         // key/8
      int qa = wave * 32 + l16, qb = wave * 32 + 16 + l16;
      h8_t pf0 = *(const h8_t*)&Pl[qa * 64 + ((chunk ^ (l16 & 7)) & 7) * 8];
      h8_t pf1 = *(const h8_t*)&Pl[qb * 64 + ((chunk ^ (l16 & 7)) & 7) * 8];
#pragma unroll
      for (int t = 0; t < 8; t++) {
        int c = t * 16 + l16;
        h8_t vf = *(const h8_t*)&Vl[c * 64 + ((chunk ^ (c & 7)) & 7) * 8];
        O[0][t] = __builtin_amdgcn_mfma_f32_16x16x32_f16(pf0, vf, O[0][t], 0, 0, 0);
        O[1][t] = __builtin_amdgcn_mfma_f32_16x16x32_f16(pf1, vf, O[1][t], 0, 0, 0);
      }
    }
  }

  // flush partials via f32 atomics
#pragma unroll
  for (int qi = 0; qi < 2; qi++)
#pragma unroll
    for (int r = 0; r < 4; r++) {
      float v = l_r[qi][r];
      v += __shfl_xor(v, 1); v += __shfl_xor(v, 2);
      v += __shfl_xor(v, 4); v += __shfl_xor(v, 8);
      if (l16 == 0)
        atomicAdd(&l_acc[b * NTOK + q0 + wave * 32 + qi * 16 + quad * 4 + r], v);
    }
#pragma unroll
  for (int qi = 0; qi < 2; qi++)
#pragma unroll
    for (int t = 0; t < 8; t++)
#pragma unroll
      for (int r = 0; r < 4; r++)
        atomicAdd(&gcn_acc[(size_t)(b * NTOK + q0 + wave * 32 + qi * 16 + quad * 4 + r)
                               * CMID + t * 16 + l16],
                  O[qi][t][r]);
}

// ---------------------------------------------------------------------------
// Kernel C: conv1 via MFMA (FROZEN from R9).
// ---------------------------------------------------------------------------
__global__ __launch_bounds__(256) void conv1_kernel(
    const float* __restrict__ gcn_acc, const float* __restrict__ l_acc,
    const float* __restrict__ Wc1,
    _Float16* __restrict__ g1t, float* __restrict__ sum1, float* __restrict__ sq1)
{
  const int b  = blockIdx.z;
  const int n0 = blockIdx.x * 64;
  const int o0 = blockIdx.y * 64;
  const int tid = threadIdx.x;
  const int wave = tid >> 6, lane = tid & 63, quad = lane >> 4, l16 = lane & 15;

  __shared__ _Float16 Gl[64][136];   // [n][c]
  __shared__ _Float16 Wcl[64][136];  // [o][c]
  __shared__ float rl[64];
  __shared__ float ssum[64], ssq[64];

  if (tid < 64) {
    rl[tid] = 1.0f / l_acc[b * NTOK + n0 + tid];
    ssum[tid] = 0.f; ssq[tid] = 0.f;
  }
  __syncthreads();

#pragma unroll
  for (int it = 0; it < 4; it++) {
    int idx = tid + it * 256;
    int n = idx >> 4, oc = idx & 15;
    const float* gp = &gcn_acc[(size_t)(b * NTOK + n0 + n) * CMID + oc * 8];
    float s = rl[n];
    f4_t a = *(const f4_t*)gp, c = *(const f4_t*)(gp + 4);
    h8_t h;
#pragma unroll
    for (int u = 0; u < 4; u++) {
      h[u] = (_Float16)(a[u] * s);
      h[u + 4] = (_Float16)(c[u] * s);
    }
    *(h8_t*)&Gl[n][oc * 8] = h;
  }
#pragma unroll
  for (int it = 0; it < 4; it++) {
    int idx = tid + it * 256;
    int row = idx >> 4, oc = idx & 15;
    *(h8_t*)&Wcl[row][oc * 8] =
        cvt_f32x8_h8(&Wc1[(size_t)(o0 + row) * 128 + oc * 8]);
  }
  __syncthreads();

  f4_t acc[4];
#pragma unroll
  for (int t = 0; t < 4; t++) acc[t] = (f4_t)(0.f);
#pragma unroll
  for (int ko = 0; ko < 4; ko++) {
    h8_t af = *(const h8_t*)&Gl[wave * 16 + l16][ko * 32 + quad * 8];
#pragma unroll
    for (int t = 0; t < 4; t++) {
      h8_t bf = *(const h8_t*)&Wcl[t * 16 + l16][ko * 32 + quad * 8];
      acc[t] = __builtin_amdgcn_mfma_f32_16x16x32_f16(af, bf, acc[t], 0, 0, 0);
    }
  }

  // D: row = n (wave*16+quad*4+r), col = o (t*16+l16)
#pragma unroll
  for (int t = 0; t < 4; t++) {
    int ol = t * 16 + l16;
    float ls = 0.f, lq = 0.f;
#pragma unroll
    for (int r = 0; r < 4; r++) {
      float v = acc[t][r];
      ls += v; lq += v * v;
      g1t[(size_t)(b * NTOK + n0 + wave * 16 + quad * 4 + r) * 256 + o0 + ol] =
          (_Float16)v;
    }
    atomicAdd(&ssum[ol], ls);
    atomicAdd(&ssq[ol], lq);
  }
  __syncthreads();
  if (tid < 64) {
    atomicAdd(&sum1[o0 + tid], ssum[tid]);
    atomicAdd(&sq1[o0 + tid], ssq[tid]);
  }
}

// ---------------------------------------------------------------------------
// Kernel E: out2 via MFMA (FROZEN from R9).
// ---------------------------------------------------------------------------
__global__ __launch_bounds__(256) void out_kernel(
    const float* __restrict__ x, const _Float16* __restrict__ g1t,
    const float* __restrict__ Wout,
    const float* __restrict__ sum1, const float* __restrict__ sq1,
    const float* __restrict__ gamma1, const float* __restrict__ beta1,
    _Float16* __restrict__ out2, float* __restrict__ sum2, float* __restrict__ sq2)
{
  const int b  = blockIdx.z;
  const int n0 = blockIdx.x * 64;
  const int o0 = blockIdx.y * 64;
  const int tid = threadIdx.x;
  const int wave = tid >> 6, lane = tid & 63, quad = lane >> 4, l16 = lane & 15;

  __shared__ _Float16 Wol[64][136];  // A tile [o][k-chunk]
  __shared__ _Float16 Bl[64][136];   // B tile [n][k-chunk]
  __shared__ _Float16 Tt[128][68];   // transpose staging (f16)
  __shared__ _Float16 scs[256], shs[256];
  __shared__ float ssum[64], ssq[64];

  {  // BN1 params inline
    float m = sum1[tid] * (1.f / NSTAT);
    float var = sq1[tid] * (1.f / NSTAT) - m * m;
    float s = gamma1[tid] * rsqrtf(var + 1e-5f);
    scs[tid] = (_Float16)s;
    shs[tid] = (_Float16)(beta1[tid] - m * s);
  }
  if (tid < 64) { ssum[tid] = 0.f; ssq[tid] = 0.f; }

  f4_t acc[4];
#pragma unroll
  for (int t = 0; t < 4; t++) acc[t] = (f4_t)(0.f);

  for (int kc = 0; kc < 512; kc += 128) {
    __syncthreads();
#pragma unroll
    for (int it = 0; it < 4; it++) {
      int idx = tid + it * 256;
      int row = idx >> 4, oc = idx & 15;
      *(h8_t*)&Wol[row][oc * 8] =
          cvt_f32x8_h8(&Wout[(size_t)(o0 + row) * 512 + kc + oc * 8]);
    }
    if (kc < 256) {
#pragma unroll
      for (int it = 0; it < 8; it++) {
        int idx = tid + it * 256;
        int cl = idx >> 4, u = idx & 15;
        f4_t v = *(const f4_t*)&x[(size_t)(b * 256 + kc + cl) * NTOK + n0 + u * 4];
        h4_t h;
#pragma unroll
        for (int j = 0; j < 4; j++) h[j] = (_Float16)v[j];
        *(h4_t*)&Tt[cl][u * 4] = h;
      }
      __syncthreads();
#pragma unroll
      for (int it = 0; it < 4; it++) {
        int idx = tid + it * 256;
        int nl = idx & 63, oc = idx >> 6;
        h8_t h;
#pragma unroll
        for (int j = 0; j < 8; j++) h[j] = Tt[oc * 8 + j][nl];
        *(h8_t*)&Bl[nl][oc * 8] = h;
      }
    } else {
#pragma unroll
      for (int it = 0; it < 4; it++) {
        int idx = tid + it * 256;
        int n = idx >> 4, oc = idx & 15;
        int cg = kc - 256 + oc * 8;
        h8_t g = *(const h8_t*)&g1t[(size_t)(b * NTOK + n0 + n) * 256 + cg];
        h8_t h;
#pragma unroll
        for (int u = 0; u < 8; u++) {
          float t = (float)scs[cg + u] * (float)g[u] + (float)shs[cg + u];
          h[u] = (_Float16)(t > 0.f ? t : 0.f);
        }
        *(h8_t*)&Bl[n][oc * 8] = h;
      }
    }
    __syncthreads();
#pragma unroll
    for (int ko = 0; ko < 4; ko++) {
      h8_t af = *(const h8_t*)&Wol[wave * 16 + l16][ko * 32 + quad * 8];
#pragma unroll
      for (int t = 0; t < 4; t++) {
        h8_t bf = *(const h8_t*)&Bl[t * 16 + l16][ko * 32 + quad * 8];
        acc[t] = __builtin_amdgcn_mfma_f32_16x16x32_f16(af, bf, acc[t], 0, 0, 0);
      }
    }
  }

#pragma unroll
  for (int r = 0; r < 4; r++) {
    int o = o0 + wave * 16 + quad * 4 + r;
    float ls = 0.f, lq = 0.f;
#pragma unroll
    for (int t = 0; t < 4; t++) {
      float v = acc[t][r];
      ls += v; lq += v * v;
      out2[(size_t)(b * 256 + o) * NTOK + n0 + t * 16 + l16] = (_Float16)v;
    }
    atomicAdd(&ssum[wave * 16 + quad * 4 + r], ls);
    atomicAdd(&ssq[wave * 16 + quad * 4 + r], lq);
  }
  __syncthreads();
  if (tid < 64) {
    atomicAdd(&sum2[o0 + tid], ssum[tid]);
    atomicAdd(&sq2[o0 + tid], ssq[tid]);
  }
}

// ---------------------------------------------------------------------------
// Kernel G: out = relu(sc2*out2 + sh2); BN2 params inline (FROZEN from R9).
// ---------------------------------------------------------------------------
__global__ __launch_bounds__(256) void bn2_kernel(
    const _Float16* __restrict__ out2, const float* __restrict__ sum2,
    const float* __restrict__ sq2, const float* __restrict__ gamma2,
    const float* __restrict__ beta2, float* __restrict__ out)
{
  size_t i = ((size_t)blockIdx.x * 256 + threadIdx.x) * 8;
  int o = (int)((i / NTOK) & 255);
  float m = sum2[o] * (1.f / NSTAT);
  float var = sq2[o] * (1.f / NSTAT) - m * m;
  float s = gamma2[o] * rsqrtf(var + 1e-5f);
  float h = beta2[o] - m * s;
  h8_t v = *(const h8_t*)&out2[i];
  f4_t r0, r1;
#pragma unroll
  for (int u = 0; u < 4; u++) {
    float t0 = s * (float)v[u] + h;
    float t1 = s * (float)v[u + 4] + h;
    r0[u] = t0 > 0.f ? t0 : 0.f;
    r1[u] = t1 > 0.f ? t1 : 0.f;
  }
  *(f4_t*)&out[i] = r0;
  *(f4_t*)&out[i + 4] = r1;
}

// ---------------------------------------------------------------------------
// ws (18.89 MB, known-safe): [0,8K) stats; base: R0..R3 (4.72 MB each):
//   Qt(R0) Kt(R1) V(R2); g1t[n][256] aliases R0+R1 (dead after flash);
//   out2[o][n] aliases R2+R3.  d_out = flash scratch (gcn_acc+l_acc).
// ---------------------------------------------------------------------------
extern "C" void kernel_launch(void* const* d_in, const int* in_sizes, int n_in,
                              void* d_out, int out_size, void* d_ws, size_t ws_size,
                              hipStream_t stream) {
  const float* x      = (const float*)d_in[0];
  const float* Wk     = (const float*)d_in[1];
  const float* Wv     = (const float*)d_in[2];
  const float* Wq     = (const float*)d_in[3];
  const float* Wc1    = (const float*)d_in[4];
  const float* gamma1 = (const float*)d_in[5];
  const float* beta1  = (const float*)d_in[6];
  const float* Wout   = (const float*)d_in[7];
  const float* gamma2 = (const float*)d_in[8];
  const float* beta2  = (const float*)d_in[9];
  float* out = (float*)d_out;

  char* ws = (char*)d_ws;
  float* sum1 = (float*)(ws + 0 * 1024);
  float* sq1  = (float*)(ws + 1 * 1024);
  float* sum2 = (float*)(ws + 2 * 1024);
  float* sq2  = (float*)(ws + 3 * 1024);

  const size_t R = (size_t)NBATCH * NTOK * CMID * 2;  // 4,718,592 B per region
  char* base = ws + 8 * 1024;
  _Float16* Qt   = (_Float16*)(base + 0 * R);
  _Float16* Kt   = (_Float16*)(base + 1 * R);
  _Float16* V    = (_Float16*)(base + 2 * R);
  _Float16* g1t  = (_Float16*)(base + 0 * R);  // [b][n][256], aliases Qt+Kt
  _Float16* out2 = (_Float16*)(base + 2 * R);  // [b][o][n],   aliases V+spare

  float* gcn_acc = (float*)d_out;                              // 9,437,184 B
  float* l_acc   = (float*)((char*)d_out + (size_t)NBATCH * NTOK * CMID * 4);

  hipMemsetAsync(sum1, 0, 4 * 1024, stream);
  hipMemsetAsync(gcn_acc, 0,
                 (size_t)NBATCH * NTOK * CMID * 4 + (size_t)NBATCH * NTOK * 4,
                 stream);

  qkv_kernel<<<dim3(144, 6, 2), 256, 0, stream>>>(x, Wk, Wv, Wq, Qt, Kt, V);
  flash_kernel<<<dim3(72, KCHUNK, 2), 256, 0, stream>>>(Qt, Kt, V, gcn_acc, l_acc);
  conv1_kernel<<<dim3(144, 4, 2), 256, 0, stream>>>(gcn_acc, l_acc, Wc1, g1t, sum1, sq1);
  out_kernel<<<dim3(144, 4, 2), 256, 0, stream>>>(x, g1t, Wout, sum1, sq1, gamma1, beta1,
                                                  out2, sum2, sq2);
  bn2_kernel<<<2304, 256, 0, stream>>>(out2, sum2, sq2, gamma2, beta2, out);
}

// Round 11
// 570.931 us; speedup vs baseline: 1.2340x; 1.2340x over previous
//
#include <hip/hip_runtime.h>

typedef _Float16 h8_t __attribute__((ext_vector_type(8)));
typedef _Float16 h4_t __attribute__((ext_vector_type(4)));
typedef float f4_t __attribute__((ext_vector_type(4)));

#define NTOK 9216
#define CMID 128
#define NBATCH 2
#define KCHUNK 5                  // 720 blocks: all resident at 3 blocks/CU
#define NKT 144                   // 64-key tiles per batch
#define NSTAT 18432.0f            // 2*9216 elements per channel for BN stats

// MFMA fragment recipe (verified R2-R10):
//   A-frag: lane(l16,quad) holds A[m=l16][k=quad*8+j]   (h8 from [m][k] row)
//   B-frag: lane(l16,quad) holds B[n=l16][k=quad*8+j]   (h8 from [n][k] row)
//   D:      lane(l16,quad) holds D[row=quad*4+r][col=l16]
// R8 lesson: W frags must be LDS-staged (in-loop per-lane global loads = L2
//   latency on critical path).
// R6/R10 lesson: unified VGPR+AGPR cap; prefetch regs live across MFMA
//   phases spill -> FETCH/WRITE_SIZE explosion. Stage inline instead.
// R10 win: XOR-swizzled LDS verified (SQ_LDS_BANK_CONFLICT = 0, correct).

__device__ __forceinline__ h8_t cvt_f32x8_h8(const float* p) {
  f4_t a = *(const f4_t*)p, b = *(const f4_t*)(p + 4);
  h8_t h;
#pragma unroll
  for (int u = 0; u < 4; u++) { h[u] = (_Float16)a[u]; h[u + 4] = (_Float16)b[u]; }
  return h;
}

// ---------------------------------------------------------------------------
// Kernel A: QKV projection via MFMA (FROZEN from R9).
// ---------------------------------------------------------------------------
__global__ __launch_bounds__(256) void qkv_kernel(
    const float* __restrict__ x, const float* __restrict__ Wk,
    const float* __restrict__ Wv, const float* __restrict__ Wq,
    _Float16* __restrict__ Qt, _Float16* __restrict__ Kt,
    _Float16* __restrict__ V)
{
  const int b  = blockIdx.z;
  const int n0 = blockIdx.x * 64;
  const int o0 = blockIdx.y * 64;
  const int tid = threadIdx.x;
  const int wave = tid >> 6, lane = tid & 63, quad = lane >> 4, l16 = lane & 15;

  __shared__ _Float16 Wl[64][136];   // A tile [o][c-chunk]
  __shared__ _Float16 xl[64][136];   // B tile [n][c-chunk]
  __shared__ _Float16 Tt[128][68];   // transpose staging (f16)

  const float* Wsel; int orow;
  if (o0 < 128)      { Wsel = Wq; orow = o0; }
  else if (o0 < 256) { Wsel = Wk; orow = o0 - 128; }
  else               { Wsel = Wv; orow = o0 - 256; }

  f4_t acc[4];
#pragma unroll
  for (int t = 0; t < 4; t++) acc[t] = (f4_t)(0.f);

  for (int kc = 0; kc < 256; kc += 128) {
    __syncthreads();
#pragma unroll
    for (int it = 0; it < 4; it++) {
      int idx = tid + it * 256;
      int row = idx >> 4, oc = idx & 15;
      *(h8_t*)&Wl[row][oc * 8] =
          cvt_f32x8_h8(&Wsel[(size_t)(orow + row) * 256 + kc + oc * 8]);
    }
#pragma unroll
    for (int it = 0; it < 8; it++) {
      int idx = tid + it * 256;
      int cl = idx >> 4, u = idx & 15;
      f4_t v = *(const f4_t*)&x[(size_t)(b * 256 + kc + cl) * NTOK + n0 + u * 4];
      h4_t h;
#pragma unroll
      for (int j = 0; j < 4; j++) h[j] = (_Float16)v[j];
      *(h4_t*)&Tt[cl][u * 4] = h;
    }
    __syncthreads();
#pragma unroll
    for (int it = 0; it < 4; it++) {
      int idx = tid + it * 256;
      int nl = idx & 63, oc = idx >> 6;   // oc 0..15
      h8_t h;
#pragma unroll
      for (int j = 0; j < 8; j++) h[j] = Tt[oc * 8 + j][nl];
      *(h8_t*)&xl[nl][oc * 8] = h;
    }
    __syncthreads();
#pragma unroll
    for (int ko = 0; ko < 4; ko++) {
      h8_t af = *(const h8_t*)&Wl[wave * 16 + l16][ko * 32 + quad * 8];
#pragma unroll
      for (int t = 0; t < 4; t++) {
        h8_t bf = *(const h8_t*)&xl[t * 16 + l16][ko * 32 + quad * 8];
        acc[t] = __builtin_amdgcn_mfma_f32_16x16x32_f16(af, bf, acc[t], 0, 0, 0);
      }
    }
  }

  const float qscale = 0.08838834764831845f * 1.4426950408889634f; // 128^-0.5*log2e
  if (o0 < 256) {
    _Float16* dst = (o0 < 128) ? Qt : Kt;
    const int od = ((o0 < 128) ? o0 : (o0 - 128)) + wave * 16 + quad * 4;
    const float s = (o0 < 128) ? qscale : 1.0f;
#pragma unroll
    for (int t = 0; t < 4; t++) {
      int n = n0 + t * 16 + l16;
      h4_t h;
#pragma unroll
      for (int r = 0; r < 4; r++) h[r] = (_Float16)(acc[t][r] * s);
      *(h4_t*)&dst[(size_t)(b * NTOK + n) * CMID + od] = h;
    }
  } else {
    const int c0 = o0 - 256 + wave * 16 + quad * 4;
#pragma unroll
    for (int t = 0; t < 4; t++) {
      int n = n0 + t * 16 + l16;
#pragma unroll
      for (int r = 0; r < 4; r++)
        V[(size_t)(b * CMID + c0 + r) * NTOK + n] = (_Float16)acc[t][r];
    }
  }
}

// ---------------------------------------------------------------------------
// Kernel B v6: split-K flash.
//  - XOR-swizzled no-pad LDS (R10-verified: 0 bank conflicts, correct):
//    Kl[64][128] chunk^=row&15; Vl/Pl[.][64] chunk^=row&7.  48 KB total.
//  - Separate wave-private Pl -> only 2 barriers/iter (no Kl/Pl alias B3).
//  - Staging INLINE global->LDS at loop top (R7 pattern, 84 VGPR, no
//    live-across-phase prefetch regs -> no spills).
// ---------------------------------------------------------------------------
__global__ __launch_bounds__(256, 3) void flash_kernel(
    const _Float16* __restrict__ Qt, const _Float16* __restrict__ Kt,
    const _Float16* __restrict__ V,
    float* __restrict__ gcn_acc, float* __restrict__ l_acc)
{
  const int b  = blockIdx.z;
  const int kc = blockIdx.y;
  const int q0 = blockIdx.x * 128;
  const int tid = threadIdx.x;
  const int wave = tid >> 6, lane = tid & 63, quad = lane >> 4, l16 = lane & 15;

  __shared__ alignas(16) _Float16 Kl[64 * 128];   // [key][c]  swizzled
  __shared__ alignas(16) _Float16 Vl[128 * 64];   // [c][key]  swizzled
  __shared__ alignas(16) _Float16 Pl[128 * 64];   // [q][key]  swizzled, wave-private

  h8_t qf[2][4];
#pragma unroll
  for (int qi = 0; qi < 2; qi++) {
    const _Float16* qp =
        Qt + (size_t)(b * NTOK + q0 + wave * 32 + qi * 16 + l16) * CMID;
#pragma unroll
    for (int ch = 0; ch < 4; ch++)
      qf[qi][ch] = *(const h8_t*)(qp + ch * 32 + quad * 8);
  }

  f4_t O[2][8];
#pragma unroll
  for (int qi = 0; qi < 2; qi++)
#pragma unroll
    for (int t = 0; t < 8; t++) O[qi][t] = (f4_t)(0.f);
  float l_r[2][4] = {{0.f, 0.f, 0.f, 0.f}, {0.f, 0.f, 0.f, 0.f}};

  const int t0 = (kc * NKT) / KCHUNK;
  const int t1 = ((kc + 1) * NKT) / KCHUNK;
  for (int k0 = t0 * 64; k0 < t1 * 64; k0 += 64) {
    __syncthreads();   // B1: all waves done reading Kl/Vl/Pl of prior tile
    {  // stage K/V inline (global -> LDS, swizzled placement)
      const h8_t* src = (const h8_t*)(Kt + (size_t)(b * NTOK + k0) * CMID);
#pragma unroll
      for (int r = 0; r < 4; r++) {
        int idx = tid + r * 256;
        int row = idx >> 4, ch = idx & 15;               // Kl: key row, c-chunk
        *(h8_t*)&Kl[row * 128 + ((ch ^ row) & 15) * 8] = src[idx];
      }
      const _Float16* vs = V + (size_t)(b * CMID) * NTOK + k0;
#pragma unroll
      for (int r = 0; r < 4; r++) {
        int idx = tid + r * 256;
        int row = idx >> 3, ch = idx & 7;                // Vl: c row, key-chunk
        *(h8_t*)&Vl[row * 64 + ((ch ^ row) & 7) * 8] =
            *(const h8_t*)(vs + (size_t)row * NTOK + ch * 8);
      }
    }
    __syncthreads();   // B2: tiles staged

    // S = Q^T K : wave computes 32q x 64k
    f4_t S[2][4];
#pragma unroll
    for (int qi = 0; qi < 2; qi++)
#pragma unroll
      for (int t = 0; t < 4; t++) S[qi][t] = (f4_t)(0.f);
#pragma unroll
    for (int ch = 0; ch < 4; ch++)
#pragma unroll
      for (int t = 0; t < 4; t++) {
        int chunk = ch * 4 + quad;                       // c/8; row&15 == l16
        h8_t kf = *(const h8_t*)&Kl[(t * 16 + l16) * 128 + ((chunk ^ l16) & 15) * 8];
        S[0][t] = __builtin_amdgcn_mfma_f32_16x16x32_f16(qf[0][ch], kf, S[0][t], 0, 0, 0);
        S[1][t] = __builtin_amdgcn_mfma_f32_16x16x32_f16(qf[1][ch], kf, S[1][t], 0, 0, 0);
      }

    // p = 2^(S-8); accumulate l; write P (wave-private rows, no barrier)
#pragma unroll
    for (int qi = 0; qi < 2; qi++)
#pragma unroll
      for (int t = 0; t < 4; t++)
#pragma unroll
        for (int r = 0; r < 4; r++) {
          float p = exp2f(S[qi][t][r] - 8.0f);
          l_r[qi][r] += p;
          int q = wave * 32 + qi * 16 + quad * 4 + r;
          int key = t * 16 + l16;
          Pl[q * 64 + (((key >> 3) ^ q) & 7) * 8 + (key & 7)] = (_Float16)p;
        }

    // O += P V^T
#pragma unroll
    for (int ch = 0; ch < 2; ch++) {
      int chunk = ch * 4 + quad;                         // key/8
      int qa = wave * 32 + l16, qb = wave * 32 + 16 + l16;
      h8_t pf0 = *(const h8_t*)&Pl[qa * 64 + ((chunk ^ (l16 & 7)) & 7) * 8];
      h8_t pf1 = *(const h8_t*)&Pl[qb * 64 + ((chunk ^ (l16 & 7)) & 7) * 8];
#pragma unroll
      for (int t = 0; t < 8; t++) {
        int c = t * 16 + l16;
        h8_t vf = *(const h8_t*)&Vl[c * 64 + ((chunk ^ (c & 7)) & 7) * 8];
        O[0][t] = __builtin_amdgcn_mfma_f32_16x16x32_f16(pf0, vf, O[0][t], 0, 0, 0);
        O[1][t] = __builtin_amdgcn_mfma_f32_16x16x32_f16(pf1, vf, O[1][t], 0, 0, 0);
      }
    }
  }

  // flush partials via f32 atomics
#pragma unroll
  for (int qi = 0; qi < 2; qi++)
#pragma unroll
    for (int r = 0; r < 4; r++) {
      float v = l_r[qi][r];
      v += __shfl_xor(v, 1); v += __shfl_xor(v, 2);
      v += __shfl_xor(v, 4); v += __shfl_xor(v, 8);
      if (l16 == 0)
        atomicAdd(&l_acc[b * NTOK + q0 + wave * 32 + qi * 16 + quad * 4 + r], v);
    }
#pragma unroll
  for (int qi = 0; qi < 2; qi++)
#pragma unroll
    for (int t = 0; t < 8; t++)
#pragma unroll
      for (int r = 0; r < 4; r++)
        atomicAdd(&gcn_acc[(size_t)(b * NTOK + q0 + wave * 32 + qi * 16 + quad * 4 + r)
                               * CMID + t * 16 + l16],
                  O[qi][t][r]);
}

// ---------------------------------------------------------------------------
// Kernel C: conv1 via MFMA (FROZEN from R9).
// ---------------------------------------------------------------------------
__global__ __launch_bounds__(256) void conv1_kernel(
    const float* __restrict__ gcn_acc, const float* __restrict__ l_acc,
    const float* __restrict__ Wc1,
    _Float16* __restrict__ g1t, float* __restrict__ sum1, float* __restrict__ sq1)
{
  const int b  = blockIdx.z;
  const int n0 = blockIdx.x * 64;
  const int o0 = blockIdx.y * 64;
  const int tid = threadIdx.x;
  const int wave = tid >> 6, lane = tid & 63, quad = lane >> 4, l16 = lane & 15;

  __shared__ _Float16 Gl[64][136];   // [n][c]
  __shared__ _Float16 Wcl[64][136];  // [o][c]
  __shared__ float rl[64];
  __shared__ float ssum[64], ssq[64];

  if (tid < 64) {
    rl[tid] = 1.0f / l_acc[b * NTOK + n0 + tid];
    ssum[tid] = 0.f; ssq[tid] = 0.f;
  }
  __syncthreads();

#pragma unroll
  for (int it = 0; it < 4; it++) {
    int idx = tid + it * 256;
    int n = idx >> 4, oc = idx & 15;
    const float* gp = &gcn_acc[(size_t)(b * NTOK + n0 + n) * CMID + oc * 8];
    float s = rl[n];
    f4_t a = *(const f4_t*)gp, c = *(const f4_t*)(gp + 4);
    h8_t h;
#pragma unroll
    for (int u = 0; u < 4; u++) {
      h[u] = (_Float16)(a[u] * s);
      h[u + 4] = (_Float16)(c[u] * s);
    }
    *(h8_t*)&Gl[n][oc * 8] = h;
  }
#pragma unroll
  for (int it = 0; it < 4; it++) {
    int idx = tid + it * 256;
    int row = idx >> 4, oc = idx & 15;
    *(h8_t*)&Wcl[row][oc * 8] =
        cvt_f32x8_h8(&Wc1[(size_t)(o0 + row) * 128 + oc * 8]);
  }
  __syncthreads();

  f4_t acc[4];
#pragma unroll
  for (int t = 0; t < 4; t++) acc[t] = (f4_t)(0.f);
#pragma unroll
  for (int ko = 0; ko < 4; ko++) {
    h8_t af = *(const h8_t*)&Gl[wave * 16 + l16][ko * 32 + quad * 8];
#pragma unroll
    for (int t = 0; t < 4; t++) {
      h8_t bf = *(const h8_t*)&Wcl[t * 16 + l16][ko * 32 + quad * 8];
      acc[t] = __builtin_amdgcn_mfma_f32_16x16x32_f16(af, bf, acc[t], 0, 0, 0);
    }
  }

  // D: row = n (wave*16+quad*4+r), col = o (t*16+l16)
#pragma unroll
  for (int t = 0; t < 4; t++) {
    int ol = t * 16 + l16;
    float ls = 0.f, lq = 0.f;
#pragma unroll
    for (int r = 0; r < 4; r++) {
      float v = acc[t][r];
      ls += v; lq += v * v;
      g1t[(size_t)(b * NTOK + n0 + wave * 16 + quad * 4 + r) * 256 + o0 + ol] =
          (_Float16)v;
    }
    atomicAdd(&ssum[ol], ls);
    atomicAdd(&ssq[ol], lq);
  }
  __syncthreads();
  if (tid < 64) {
    atomicAdd(&sum1[o0 + tid], ssum[tid]);
    atomicAdd(&sq1[o0 + tid], ssq[tid]);
  }
}

// ---------------------------------------------------------------------------
// Kernel E: out2 via MFMA (FROZEN from R9).
// ---------------------------------------------------------------------------
__global__ __launch_bounds__(256) void out_kernel(
    const float* __restrict__ x, const _Float16* __restrict__ g1t,
    const float* __restrict__ Wout,
    const float* __restrict__ sum1, const float* __restrict__ sq1,
    const float* __restrict__ gamma1, const float* __restrict__ beta1,
    _Float16* __restrict__ out2, float* __restrict__ sum2, float* __restrict__ sq2)
{
  const int b  = blockIdx.z;
  const int n0 = blockIdx.x * 64;
  const int o0 = blockIdx.y * 64;
  const int tid = threadIdx.x;
  const int wave = tid >> 6, lane = tid & 63, quad = lane >> 4, l16 = lane & 15;

  __shared__ _Float16 Wol[64][136];  // A tile [o][k-chunk]
  __shared__ _Float16 Bl[64][136];   // B tile [n][k-chunk]
  __shared__ _Float16 Tt[128][68];   // transpose staging (f16)
  __shared__ _Float16 scs[256], shs[256];
  __shared__ float ssum[64], ssq[64];

  {  // BN1 params inline
    float m = sum1[tid] * (1.f / NSTAT);
    float var = sq1[tid] * (1.f / NSTAT) - m * m;
    float s = gamma1[tid] * rsqrtf(var + 1e-5f);
    scs[tid] = (_Float16)s;
    shs[tid] = (_Float16)(beta1[tid] - m * s);
  }
  if (tid < 64) { ssum[tid] = 0.f; ssq[tid] = 0.f; }

  f4_t acc[4];
#pragma unroll
  for (int t = 0; t < 4; t++) acc[t] = (f4_t)(0.f);

  for (int kc = 0; kc < 512; kc += 128) {
    __syncthreads();
#pragma unroll
    for (int it = 0; it < 4; it++) {
      int idx = tid + it * 256;
      int row = idx >> 4, oc = idx & 15;
      *(h8_t*)&Wol[row][oc * 8] =
          cvt_f32x8_h8(&Wout[(size_t)(o0 + row) * 512 + kc + oc * 8]);
    }
    if (kc < 256) {
#pragma unroll
      for (int it = 0; it < 8; it++) {
        int idx = tid + it * 256;
        int cl = idx >> 4, u = idx & 15;
        f4_t v = *(const f4_t*)&x[(size_t)(b * 256 + kc + cl) * NTOK + n0 + u * 4];
        h4_t h;
#pragma unroll
        for (int j = 0; j < 4; j++) h[j] = (_Float16)v[j];
        *(h4_t*)&Tt[cl][u * 4] = h;
      }
      __syncthreads();
#pragma unroll
      for (int it = 0; it < 4; it++) {
        int idx = tid + it * 256;
        int nl = idx & 63, oc = idx >> 6;
        h8_t h;
#pragma unroll
        for (int j = 0; j < 8; j++) h[j] = Tt[oc * 8 + j][nl];
        *(h8_t*)&Bl[nl][oc * 8] = h;
      }
    } else {
#pragma unroll
      for (int it = 0; it < 4; it++) {
        int idx = tid + it * 256;
        int n = idx >> 4, oc = idx & 15;
        int cg = kc - 256 + oc * 8;
        h8_t g = *(const h8_t*)&g1t[(size_t)(b * NTOK + n0 + n) * 256 + cg];
        h8_t h;
#pragma unroll
        for (int u = 0; u < 8; u++) {
          float t = (float)scs[cg + u] * (float)g[u] + (float)shs[cg + u];
          h[u] = (_Float16)(t > 0.f ? t : 0.f);
        }
        *(h8_t*)&Bl[n][oc * 8] = h;
      }
    }
    __syncthreads();
#pragma unroll
    for (int ko = 0; ko < 4; ko++) {
      h8_t af = *(const h8_t*)&Wol[wave * 16 + l16][ko * 32 + quad * 8];
#pragma unroll
      for (int t = 0; t < 4; t++) {
        h8_t bf = *(const h8_t*)&Bl[t * 16 + l16][ko * 32 + quad * 8];
        acc[t] = __builtin_amdgcn_mfma_f32_16x16x32_f16(af, bf, acc[t], 0, 0, 0);
      }
    }
  }

#pragma unroll
  for (int r = 0; r < 4; r++) {
    int o = o0 + wave * 16 + quad * 4 + r;
    float ls = 0.f, lq = 0.f;
#pragma unroll
    for (int t = 0; t < 4; t++) {
      float v = acc[t][r];
      ls += v; lq += v * v;
      out2[(size_t)(b * 256 + o) * NTOK + n0 + t * 16 + l16] = (_Float16)v;
    }
    atomicAdd(&ssum[wave * 16 + quad * 4 + r], ls);
    atomicAdd(&ssq[wave * 16 + quad * 4 + r], lq);
  }
  __syncthreads();
  if (tid < 64) {
    atomicAdd(&sum2[o0 + tid], ssum[tid]);
    atomicAdd(&sq2[o0 + tid], ssq[tid]);
  }
}

// ---------------------------------------------------------------------------
// Kernel G: out = relu(sc2*out2 + sh2); BN2 params inline (FROZEN from R9).
// ---------------------------------------------------------------------------
__global__ __launch_bounds__(256) void bn2_kernel(
    const _Float16* __restrict__ out2, const float* __restrict__ sum2,
    const float* __restrict__ sq2, const float* __restrict__ gamma2,
    const float* __restrict__ beta2, float* __restrict__ out)
{
  size_t i = ((size_t)blockIdx.x * 256 + threadIdx.x) * 8;
  int o = (int)((i / NTOK) & 255);
  float m = sum2[o] * (1.f / NSTAT);
  float var = sq2[o] * (1.f / NSTAT) - m * m;
  float s = gamma2[o] * rsqrtf(var + 1e-5f);
  float h = beta2[o] - m * s;
  h8_t v = *(const h8_t*)&out2[i];
  f4_t r0, r1;
#pragma unroll
  for (int u = 0; u < 4; u++) {
    float t0 = s * (float)v[u] + h;
    float t1 = s * (float)v[u + 4] + h;
    r0[u] = t0 > 0.f ? t0 : 0.f;
    r1[u] = t1 > 0.f ? t1 : 0.f;
  }
  *(f4_t*)&out[i] = r0;
  *(f4_t*)&out[i + 4] = r1;
}

// ---------------------------------------------------------------------------
// ws (18.89 MB, known-safe): [0,8K) stats; base: R0..R3 (4.72 MB each):
//   Qt(R0) Kt(R1) V(R2); g1t[n][256] aliases R0+R1 (dead after flash);
//   out2[o][n] aliases R2+R3.  d_out = flash scratch (gcn_acc+l_acc).
// ---------------------------------------------------------------------------
extern "C" void kernel_launch(void* const* d_in, const int* in_sizes, int n_in,
                              void* d_out, int out_size, void* d_ws, size_t ws_size,
                              hipStream_t stream) {
  const float* x      = (const float*)d_in[0];
  const float* Wk     = (const float*)d_in[1];
  const float* Wv     = (const float*)d_in[2];
  const float* Wq     = (const float*)d_in[3];
  const float* Wc1    = (const float*)d_in[4];
  const float* gamma1 = (const float*)d_in[5];
  const float* beta1  = (const float*)d_in[6];
  const float* Wout   = (const float*)d_in[7];
  const float* gamma2 = (const float*)d_in[8];
  const float* beta2  = (const float*)d_in[9];
  float* out = (float*)d_out;

  char* ws = (char*)d_ws;
  float* sum1 = (float*)(ws + 0 * 1024);
  float* sq1  = (float*)(ws + 1 * 1024);
  float* sum2 = (float*)(ws + 2 * 1024);
  float* sq2  = (float*)(ws + 3 * 1024);

  const size_t R = (size_t)NBATCH * NTOK * CMID * 2;  // 4,718,592 B per region
  char* base = ws + 8 * 1024;
  _Float16* Qt   = (_Float16*)(base + 0 * R);
  _Float16* Kt   = (_Float16*)(base + 1 * R);
  _Float16* V    = (_Float16*)(base + 2 * R);
  _Float16* g1t  = (_Float16*)(base + 0 * R);  // [b][n][256], aliases Qt+Kt
  _Float16* out2 = (_Float16*)(base + 2 * R);  // [b][o][n],   aliases V+spare

  float* gcn_acc = (float*)d_out;                              // 9,437,184 B
  float* l_acc   = (float*)((char*)d_out + (size_t)NBATCH * NTOK * CMID * 4);

  hipMemsetAsync(sum1, 0, 4 * 1024, stream);
  hipMemsetAsync(gcn_acc, 0,
                 (size_t)NBATCH * NTOK * CMID * 4 + (size_t)NBATCH * NTOK * 4,
                 stream);

  qkv_kernel<<<dim3(144, 6, 2), 256, 0, stream>>>(x, Wk, Wv, Wq, Qt, Kt, V);
  flash_kernel<<<dim3(72, KCHUNK, 2), 256, 0, stream>>>(Qt, Kt, V, gcn_acc, l_acc);
  conv1_kernel<<<dim3(144, 4, 2), 256, 0, stream>>>(gcn_acc, l_acc, Wc1, g1t, sum1, sq1);
  out_kernel<<<dim3(144, 4, 2), 256, 0, stream>>>(x, g1t, Wout, sum1, sq1, gamma1, beta1,
                                                  out2, sum2, sq2);
  bn2_kernel<<<2304, 256, 0, stream>>>(out2, sum2, sq2, gamma2, beta2, out);
}

// Round 12
// 338.349 us; speedup vs baseline: 2.0822x; 1.6874x over previous
//
#include <hip/hip_runtime.h>

typedef _Float16 h8_t __attribute__((ext_vector_type(8)));
typedef _Float16 h4_t __attribute__((ext_vector_type(4)));
typedef float f4_t __attribute__((ext_vector_type(4)));

#define NTOK 9216
#define CMID 128
#define NBATCH 2
#define KCHUNK 5                  // 720 blocks: all resident at 3 blocks/CU
#define NKT 144                   // 64-key tiles per batch
#define NSTAT 18432.0f            // 2*9216 elements per channel for BN stats

// MFMA fragment recipe (verified R2-R11):
//   A-frag: lane(l16,quad) holds A[m=l16][k=quad*8+j]   (h8 from [m][k] row)
//   B-frag: lane(l16,quad) holds B[n=l16][k=quad*8+j]   (h8 from [n][k] row)
//   D:      lane(l16,quad) holds D[row=quad*4+r][col=l16]
// R8 lesson: W frags must be LDS-staged (in-loop per-lane global loads = L2
//   latency on critical path).
// R6/R10/R11 lesson: unified VGPR+AGPR cap at (256,3); extra live registers
//   OR complex per-element addressing (XOR swizzle, scattered computed
//   stores) tips the allocator into scratch -> FETCH_SIZE explosion even
//   when VGPR_Count still reads 84. Keep flash at the R7/R9 pattern.

__device__ __forceinline__ h8_t cvt_f32x8_h8(const float* p) {
  f4_t a = *(const f4_t*)p, b = *(const f4_t*)(p + 4);
  h8_t h;
#pragma unroll
  for (int u = 0; u < 4; u++) { h[u] = (_Float16)a[u]; h[u + 4] = (_Float16)b[u]; }
  return h;
}

// ---------------------------------------------------------------------------
// Kernel A: QKV projection via MFMA (R9 + coalesced V epilogue: V-branch
// routes acc through dead xl tile -> 2 h8 stores/thread instead of 16 b16).
// ---------------------------------------------------------------------------
__global__ __launch_bounds__(256) void qkv_kernel(
    const float* __restrict__ x, const float* __restrict__ Wk,
    const float* __restrict__ Wv, const float* __restrict__ Wq,
    _Float16* __restrict__ Qt, _Float16* __restrict__ Kt,
    _Float16* __restrict__ V)
{
  const int b  = blockIdx.z;
  const int n0 = blockIdx.x * 64;
  const int o0 = blockIdx.y * 64;
  const int tid = threadIdx.x;
  const int wave = tid >> 6, lane = tid & 63, quad = lane >> 4, l16 = lane & 15;

  __shared__ _Float16 Wl[64][136];   // A tile [o][c-chunk]
  __shared__ _Float16 xl[64][136];   // B tile [n][c-chunk]; reused as V staging
  __shared__ _Float16 Tt[128][68];   // transpose staging (f16)

  const float* Wsel; int orow;
  if (o0 < 128)      { Wsel = Wq; orow = o0; }
  else if (o0 < 256) { Wsel = Wk; orow = o0 - 128; }
  else               { Wsel = Wv; orow = o0 - 256; }

  f4_t acc[4];
#pragma unroll
  for (int t = 0; t < 4; t++) acc[t] = (f4_t)(0.f);

  for (int kc = 0; kc < 256; kc += 128) {
    __syncthreads();
#pragma unroll
    for (int it = 0; it < 4; it++) {
      int idx = tid + it * 256;
      int row = idx >> 4, oc = idx & 15;
      *(h8_t*)&Wl[row][oc * 8] =
          cvt_f32x8_h8(&Wsel[(size_t)(orow + row) * 256 + kc + oc * 8]);
    }
#pragma unroll
    for (int it = 0; it < 8; it++) {
      int idx = tid + it * 256;
      int cl = idx >> 4, u = idx & 15;
      f4_t v = *(const f4_t*)&x[(size_t)(b * 256 + kc + cl) * NTOK + n0 + u * 4];
      h4_t h;
#pragma unroll
      for (int j = 0; j < 4; j++) h[j] = (_Float16)v[j];
      *(h4_t*)&Tt[cl][u * 4] = h;
    }
    __syncthreads();
#pragma unroll
    for (int it = 0; it < 4; it++) {
      int idx = tid + it * 256;
      int nl = idx & 63, oc = idx >> 6;   // oc 0..15
      h8_t h;
#pragma unroll
      for (int j = 0; j < 8; j++) h[j] = Tt[oc * 8 + j][nl];
      *(h8_t*)&xl[nl][oc * 8] = h;
    }
    __syncthreads();
#pragma unroll
    for (int ko = 0; ko < 4; ko++) {
      h8_t af = *(const h8_t*)&Wl[wave * 16 + l16][ko * 32 + quad * 8];
#pragma unroll
      for (int t = 0; t < 4; t++) {
        h8_t bf = *(const h8_t*)&xl[t * 16 + l16][ko * 32 + quad * 8];
        acc[t] = __builtin_amdgcn_mfma_f32_16x16x32_f16(af, bf, acc[t], 0, 0, 0);
      }
    }
  }

  const float qscale = 0.08838834764831845f * 1.4426950408889634f; // 128^-0.5*log2e
  if (o0 < 256) {
    _Float16* dst = (o0 < 128) ? Qt : Kt;
    const int od = ((o0 < 128) ? o0 : (o0 - 128)) + wave * 16 + quad * 4;
    const float s = (o0 < 128) ? qscale : 1.0f;
#pragma unroll
    for (int t = 0; t < 4; t++) {
      int n = n0 + t * 16 + l16;
      h4_t h;
#pragma unroll
      for (int r = 0; r < 4; r++) h[r] = (_Float16)(acc[t][r] * s);
      *(h4_t*)&dst[(size_t)(b * NTOK + n) * CMID + od] = h;
    }
  } else {
    // V branch: transpose acc through xl (dead after MFMA) -> coalesced h8
    __syncthreads();   // all waves done reading xl
    const int cl0 = wave * 16 + quad * 4;   // local channel row base
#pragma unroll
    for (int t = 0; t < 4; t++)
#pragma unroll
      for (int r = 0; r < 4; r++)
        xl[cl0 + r][t * 16 + l16] = (_Float16)acc[t][r];   // [c][n], pitch 136
    __syncthreads();
    const int c0 = o0 - 256;
#pragma unroll
    for (int it = 0; it < 2; it++) {
      int idx = tid + it * 256;
      int row = idx >> 3, ch = idx & 7;     // row: 64 channels, ch: 8 h8-chunks
      *(h8_t*)&V[(size_t)(b * CMID + c0 + row) * NTOK + n0 + ch * 8] =
          *(const h8_t*)&xl[row][ch * 8];
    }
  }
}

// ---------------------------------------------------------------------------
// Kernel B: split-K flash (RESTORED R9-exact — 182 us verified; all four
// variants beyond this — dbuf regs, 4-wave cap, swizzle+2-barrier — spilled
// or starved occupancy).
// ---------------------------------------------------------------------------
__global__ __launch_bounds__(256, 3) void flash_kernel(
    const _Float16* __restrict__ Qt, const _Float16* __restrict__ Kt,
    const _Float16* __restrict__ V,
    float* __restrict__ gcn_acc, float* __restrict__ l_acc)
{
  const int b  = blockIdx.z;
  const int kc = blockIdx.y;
  const int q0 = blockIdx.x * 128;
  const int tid = threadIdx.x;
  const int wave = tid >> 6, lane = tid & 63, quad = lane >> 4, l16 = lane & 15;

  __shared__ _Float16 Vl[128][72];             // [c][key]
  __shared__ alignas(16) _Float16 UBuf[9216];  // union: Kl[64][136] | Pl[128][72]
#define KL(r, c) UBuf[(r) * 136 + (c)]
#define PL(r, c) UBuf[(r) * 72 + (c)]

  h8_t qf[2][4];
#pragma unroll
  for (int qi = 0; qi < 2; qi++) {
    const _Float16* qp =
        Qt + (size_t)(b * NTOK + q0 + wave * 32 + qi * 16 + l16) * CMID;
#pragma unroll
    for (int ch = 0; ch < 4; ch++)
      qf[qi][ch] = *(const h8_t*)(qp + ch * 32 + quad * 8);
  }

  f4_t O[2][8];
#pragma unroll
  for (int qi = 0; qi < 2; qi++)
#pragma unroll
    for (int t = 0; t < 8; t++) O[qi][t] = (f4_t)(0.f);
  float l_r[2][4] = {{0.f, 0.f, 0.f, 0.f}, {0.f, 0.f, 0.f, 0.f}};

  const int t0 = (kc * NKT) / KCHUNK;
  const int t1 = ((kc + 1) * NKT) / KCHUNK;
  for (int k0 = t0 * 64; k0 < t1 * 64; k0 += 64) {
    __syncthreads();   // B1: prior iter's Pl/Vl reads complete
    {
      const h8_t* src = (const h8_t*)(Kt + (size_t)(b * NTOK + k0) * CMID);
#pragma unroll
      for (int r = 0; r < 4; r++) {
        int idx = tid + r * 256;
        int row = idx >> 4, ch = idx & 15;
        *(h8_t*)&KL(row, ch * 8) = src[idx];
      }
      const _Float16* vs = V + (size_t)(b * CMID) * NTOK + k0;
#pragma unroll
      for (int r = 0; r < 4; r++) {
        int idx = tid + r * 256;
        int row = idx >> 3, ch = idx & 7;
        *(h8_t*)&Vl[row][ch * 8] = *(const h8_t*)(vs + (size_t)row * NTOK + ch * 8);
      }
    }
    __syncthreads();   // B2: tiles staged

    f4_t S[2][4];
#pragma unroll
    for (int qi = 0; qi < 2; qi++)
#pragma unroll
      for (int t = 0; t < 4; t++) S[qi][t] = (f4_t)(0.f);
#pragma unroll
    for (int ch = 0; ch < 4; ch++)
#pragma unroll
      for (int t = 0; t < 4; t++) {
        h8_t kf = *(const h8_t*)&KL(t * 16 + l16, ch * 32 + quad * 8);
        S[0][t] = __builtin_amdgcn_mfma_f32_16x16x32_f16(qf[0][ch], kf, S[0][t], 0, 0, 0);
        S[1][t] = __builtin_amdgcn_mfma_f32_16x16x32_f16(qf[1][ch], kf, S[1][t], 0, 0, 0);
      }
    __syncthreads();   // B3: Kl reads done; region becomes Pl

#pragma unroll
    for (int qi = 0; qi < 2; qi++)
#pragma unroll
      for (int t = 0; t < 4; t++)
#pragma unroll
        for (int r = 0; r < 4; r++) {
          float p = exp2f(S[qi][t][r] - 8.0f);
          l_r[qi][r] += p;
          PL(wave * 32 + qi * 16 + quad * 4 + r, t * 16 + l16) = (_Float16)p;
        }

#pragma unroll
    for (int ch = 0; ch < 2; ch++) {
      h8_t pf0 = *(const h8_t*)&PL(wave * 32 + l16, ch * 32 + quad * 8);
      h8_t pf1 = *(const h8_t*)&PL(wave * 32 + 16 + l16, ch * 32 + quad * 8);
#pragma unroll
      for (int t = 0; t < 8; t++) {
        h8_t vf = *(const h8_t*)&Vl[t * 16 + l16][ch * 32 + quad * 8];
        O[0][t] = __builtin_amdgcn_mfma_f32_16x16x32_f16(pf0, vf, O[0][t], 0, 0, 0);
        O[1][t] = __builtin_amdgcn_mfma_f32_16x16x32_f16(pf1, vf, O[1][t], 0, 0, 0);
      }
    }
  }
#undef KL
#undef PL

#pragma unroll
  for (int qi = 0; qi < 2; qi++)
#pragma unroll
    for (int r = 0; r < 4; r++) {
      float v = l_r[qi][r];
      v += __shfl_xor(v, 1); v += __shfl_xor(v, 2);
      v += __shfl_xor(v, 4); v += __shfl_xor(v, 8);
      if (l16 == 0)
        atomicAdd(&l_acc[b * NTOK + q0 + wave * 32 + qi * 16 + quad * 4 + r], v);
    }
#pragma unroll
  for (int qi = 0; qi < 2; qi++)
#pragma unroll
    for (int t = 0; t < 8; t++)
#pragma unroll
      for (int r = 0; r < 4; r++)
        atomicAdd(&gcn_acc[(size_t)(b * NTOK + q0 + wave * 32 + qi * 16 + quad * 4 + r)
                               * CMID + t * 16 + l16],
                  O[qi][t][r]);
}

// ---------------------------------------------------------------------------
// Kernel C: conv1 via MFMA (FROZEN from R9).
// ---------------------------------------------------------------------------
__global__ __launch_bounds__(256) void conv1_kernel(
    const float* __restrict__ gcn_acc, const float* __restrict__ l_acc,
    const float* __restrict__ Wc1,
    _Float16* __restrict__ g1t, float* __restrict__ sum1, float* __restrict__ sq1)
{
  const int b  = blockIdx.z;
  const int n0 = blockIdx.x * 64;
  const int o0 = blockIdx.y * 64;
  const int tid = threadIdx.x;
  const int wave = tid >> 6, lane = tid & 63, quad = lane >> 4, l16 = lane & 15;

  __shared__ _Float16 Gl[64][136];   // [n][c]
  __shared__ _Float16 Wcl[64][136];  // [o][c]
  __shared__ float rl[64];
  __shared__ float ssum[64], ssq[64];

  if (tid < 64) {
    rl[tid] = 1.0f / l_acc[b * NTOK + n0 + tid];
    ssum[tid] = 0.f; ssq[tid] = 0.f;
  }
  __syncthreads();

#pragma unroll
  for (int it = 0; it < 4; it++) {
    int idx = tid + it * 256;
    int n = idx >> 4, oc = idx & 15;
    const float* gp = &gcn_acc[(size_t)(b * NTOK + n0 + n) * CMID + oc * 8];
    float s = rl[n];
    f4_t a = *(const f4_t*)gp, c = *(const f4_t*)(gp + 4);
    h8_t h;
#pragma unroll
    for (int u = 0; u < 4; u++) {
      h[u] = (_Float16)(a[u] * s);
      h[u + 4] = (_Float16)(c[u] * s);
    }
    *(h8_t*)&Gl[n][oc * 8] = h;
  }
#pragma unroll
  for (int it = 0; it < 4; it++) {
    int idx = tid + it * 256;
    int row = idx >> 4, oc = idx & 15;
    *(h8_t*)&Wcl[row][oc * 8] =
        cvt_f32x8_h8(&Wc1[(size_t)(o0 + row) * 128 + oc * 8]);
  }
  __syncthreads();

  f4_t acc[4];
#pragma unroll
  for (int t = 0; t < 4; t++) acc[t] = (f4_t)(0.f);
#pragma unroll
  for (int ko = 0; ko < 4; ko++) {
    h8_t af = *(const h8_t*)&Gl[wave * 16 + l16][ko * 32 + quad * 8];
#pragma unroll
    for (int t = 0; t < 4; t++) {
      h8_t bf = *(const h8_t*)&Wcl[t * 16 + l16][ko * 32 + quad * 8];
      acc[t] = __builtin_amdgcn_mfma_f32_16x16x32_f16(af, bf, acc[t], 0, 0, 0);
    }
  }

  // D: row = n (wave*16+quad*4+r), col = o (t*16+l16)
#pragma unroll
  for (int t = 0; t < 4; t++) {
    int ol = t * 16 + l16;
    float ls = 0.f, lq = 0.f;
#pragma unroll
    for (int r = 0; r < 4; r++) {
      float v = acc[t][r];
      ls += v; lq += v * v;
      g1t[(size_t)(b * NTOK + n0 + wave * 16 + quad * 4 + r) * 256 + o0 + ol] =
          (_Float16)v;
    }
    atomicAdd(&ssum[ol], ls);
    atomicAdd(&ssq[ol], lq);
  }
  __syncthreads();
  if (tid < 64) {
    atomicAdd(&sum1[o0 + tid], ssum[tid]);
    atomicAdd(&sq1[o0 + tid], ssq[tid]);
  }
}

// ---------------------------------------------------------------------------
// Kernel E: out2 via MFMA (FROZEN from R9).
// ---------------------------------------------------------------------------
__global__ __launch_bounds__(256) void out_kernel(
    const float* __restrict__ x, const _Float16* __restrict__ g1t,
    const float* __restrict__ Wout,
    const float* __restrict__ sum1, const float* __restrict__ sq1,
    const float* __restrict__ gamma1, const float* __restrict__ beta1,
    _Float16* __restrict__ out2, float* __restrict__ sum2, float* __restrict__ sq2)
{
  const int b  = blockIdx.z;
  const int n0 = blockIdx.x * 64;
  const int o0 = blockIdx.y * 64;
  const int tid = threadIdx.x;
  const int wave = tid >> 6, lane = tid & 63, quad = lane >> 4, l16 = lane & 15;

  __shared__ _Float16 Wol[64][136];  // A tile [o][k-chunk]
  __shared__ _Float16 Bl[64][136];   // B tile [n][k-chunk]
  __shared__ _Float16 Tt[128][68];   // transpose staging (f16)
  __shared__ _Float16 scs[256], shs[256];
  __shared__ float ssum[64], ssq[64];

  {  // BN1 params inline
    float m = sum1[tid] * (1.f / NSTAT);
    float var = sq1[tid] * (1.f / NSTAT) - m * m;
    float s = gamma1[tid] * rsqrtf(var + 1e-5f);
    scs[tid] = (_Float16)s;
    shs[tid] = (_Float16)(beta1[tid] - m * s);
  }
  if (tid < 64) { ssum[tid] = 0.f; ssq[tid] = 0.f; }

  f4_t acc[4];
#pragma unroll
  for (int t = 0; t < 4; t++) acc[t] = (f4_t)(0.f);

  for (int kc = 0; kc < 512; kc += 128) {
    __syncthreads();
#pragma unroll
    for (int it = 0; it < 4; it++) {
      int idx = tid + it * 256;
      int row = idx >> 4, oc = idx & 15;
      *(h8_t*)&Wol[row][oc * 8] =
          cvt_f32x8_h8(&Wout[(size_t)(o0 + row) * 512 + kc + oc * 8]);
    }
    if (kc < 256) {
#pragma unroll
      for (int it = 0; it < 8; it++) {
        int idx = tid + it * 256;
        int cl = idx >> 4, u = idx & 15;
        f4_t v = *(const f4_t*)&x[(size_t)(b * 256 + kc + cl) * NTOK + n0 + u * 4];
        h4_t h;
#pragma unroll
        for (int j = 0; j < 4; j++) h[j] = (_Float16)v[j];
        *(h4_t*)&Tt[cl][u * 4] = h;
      }
      __syncthreads();
#pragma unroll
      for (int it = 0; it < 4; it++) {
        int idx = tid + it * 256;
        int nl = idx & 63, oc = idx >> 6;
        h8_t h;
#pragma unroll
        for (int j = 0; j < 8; j++) h[j] = Tt[oc * 8 + j][nl];
        *(h8_t*)&Bl[nl][oc * 8] = h;
      }
    } else {
#pragma unroll
      for (int it = 0; it < 4; it++) {
        int idx = tid + it * 256;
        int n = idx >> 4, oc = idx & 15;
        int cg = kc - 256 + oc * 8;
        h8_t g = *(const h8_t*)&g1t[(size_t)(b * NTOK + n0 + n) * 256 + cg];
        h8_t h;
#pragma unroll
        for (int u = 0; u < 8; u++) {
          float t = (float)scs[cg + u] * (float)g[u] + (float)shs[cg + u];
          h[u] = (_Float16)(t > 0.f ? t : 0.f);
        }
        *(h8_t*)&Bl[n][oc * 8] = h;
      }
    }
    __syncthreads();
#pragma unroll
    for (int ko = 0; ko < 4; ko++) {
      h8_t af = *(const h8_t*)&Wol[wave * 16 + l16][ko * 32 + quad * 8];
#pragma unroll
      for (int t = 0; t < 4; t++) {
        h8_t bf = *(const h8_t*)&Bl[t * 16 + l16][ko * 32 + quad * 8];
        acc[t] = __builtin_amdgcn_mfma_f32_16x16x32_f16(af, bf, acc[t], 0, 0, 0);
      }
    }
  }

#pragma unroll
  for (int r = 0; r < 4; r++) {
    int o = o0 + wave * 16 + quad * 4 + r;
    float ls = 0.f, lq = 0.f;
#pragma unroll
    for (int t = 0; t < 4; t++) {
      float v = acc[t][r];
      ls += v; lq += v * v;
      out2[(size_t)(b * 256 + o) * NTOK + n0 + t * 16 + l16] = (_Float16)v;
    }
    atomicAdd(&ssum[wave * 16 + quad * 4 + r], ls);
    atomicAdd(&ssq[wave * 16 + quad * 4 + r], lq);
  }
  __syncthreads();
  if (tid < 64) {
    atomicAdd(&sum2[o0 + tid], ssum[tid]);
    atomicAdd(&sq2[o0 + tid], ssq[tid]);
  }
}

// ---------------------------------------------------------------------------
// Kernel G: out = relu(sc2*out2 + sh2); BN2 params inline (FROZEN from R9).
// ---------------------------------------------------------------------------
__global__ __launch_bounds__(256) void bn2_kernel(
    const _Float16* __restrict__ out2, const float* __restrict__ sum2,
    const float* __restrict__ sq2, const float* __restrict__ gamma2,
    const float* __restrict__ beta2, float* __restrict__ out)
{
  size_t i = ((size_t)blockIdx.x * 256 + threadIdx.x) * 8;
  int o = (int)((i / NTOK) & 255);
  float m = sum2[o] * (1.f / NSTAT);
  float var = sq2[o] * (1.f / NSTAT) - m * m;
  float s = gamma2[o] * rsqrtf(var + 1e-5f);
  float h = beta2[o] - m * s;
  h8_t v = *(const h8_t*)&out2[i];
  f4_t r0, r1;
#pragma unroll
  for (int u = 0; u < 4; u++) {
    float t0 = s * (float)v[u] + h;
    float t1 = s * (float)v[u + 4] + h;
    r0[u] = t0 > 0.f ? t0 : 0.f;
    r1[u] = t1 > 0.f ? t1 : 0.f;
  }
  *(f4_t*)&out[i] = r0;
  *(f4_t*)&out[i + 4] = r1;
}

// ---------------------------------------------------------------------------
// ws (18.89 MB, known-safe): [0,8K) stats; base: R0..R3 (4.72 MB each):
//   Qt(R0) Kt(R1) V(R2); g1t[n][256] aliases R0+R1 (dead after flash);
//   out2[o][n] aliases R2+R3.  d_out = flash scratch (gcn_acc+l_acc).
// ---------------------------------------------------------------------------
extern "C" void kernel_launch(void* const* d_in, const int* in_sizes, int n_in,
                              void* d_out, int out_size, void* d_ws, size_t ws_size,
                              hipStream_t stream) {
  const float* x      = (const float*)d_in[0];
  const float* Wk     = (const float*)d_in[1];
  const float* Wv     = (const float*)d_in[2];
  const float* Wq     = (const float*)d_in[3];
  const float* Wc1    = (const float*)d_in[4];
  const float* gamma1 = (const float*)d_in[5];
  const float* beta1  = (const float*)d_in[6];
  const float* Wout   = (const float*)d_in[7];
  const float* gamma2 = (const float*)d_in[8];
  const float* beta2  = (const float*)d_in[9];
  float* out = (float*)d_out;

  char* ws = (char*)d_ws;
  float* sum1 = (float*)(ws + 0 * 1024);
  float* sq1  = (float*)(ws + 1 * 1024);
  float* sum2 = (float*)(ws + 2 * 1024);
  float* sq2  = (float*)(ws + 3 * 1024);

  const size_t R = (size_t)NBATCH * NTOK * CMID * 2;  // 4,718,592 B per region
  char* base = ws + 8 * 1024;
  _Float16* Qt   = (_Float16*)(base + 0 * R);
  _Float16* Kt   = (_Float16*)(base + 1 * R);
  _Float16* V    = (_Float16*)(base + 2 * R);
  _Float16* g1t  = (_Float16*)(base + 0 * R);  // [b][n][256], aliases Qt+Kt
  _Float16* out2 = (_Float16*)(base + 2 * R);  // [b][o][n],   aliases V+spare

  float* gcn_acc = (float*)d_out;                              // 9,437,184 B
  float* l_acc   = (float*)((char*)d_out + (size_t)NBATCH * NTOK * CMID * 4);

  hipMemsetAsync(sum1, 0, 4 * 1024, stream);
  hipMemsetAsync(gcn_acc, 0,
                 (size_t)NBATCH * NTOK * CMID * 4 + (size_t)NBATCH * NTOK * 4,
                 stream);

  qkv_kernel<<<dim3(144, 6, 2), 256, 0, stream>>>(x, Wk, Wv, Wq, Qt, Kt, V);
  flash_kernel<<<dim3(72, KCHUNK, 2), 256, 0, stream>>>(Qt, Kt, V, gcn_acc, l_acc);
  conv1_kernel<<<dim3(144, 4, 2), 256, 0, stream>>>(gcn_acc, l_acc, Wc1, g1t, sum1, sq1);
  out_kernel<<<dim3(144, 4, 2), 256, 0, stream>>>(x, g1t, Wout, sum1, sq1, gamma1, beta1,
                                                  out2, sum2, sq2);
  bn2_kernel<<<2304, 256, 0, stream>>>(out2, sum2, sq2, gamma2, beta2, out);
}